// Round 16
// baseline (43.434 us; speedup 1.0000x reference)
//
#include <hip/hip_runtime.h>
#include <math.h>

// Problem constants (fixed by setup_inputs)
constexpr int N    = 4;
constexpr int C    = 16;
constexpr int Hin  = 288;
constexpr int Win  = 1216;
constexpr int Hout = 800;
constexpr int Wout = 400;
constexpr int PIX_PER_N = Hout * Wout;       // 320000
constexpr int CH_STRIDE = Hin * Win;         // 350208
constexpr int TOTAL = N * Hout * Wout;       // 1,280,000

typedef float v4f __attribute__((ext_vector_type(4)));

// Base-grid constants (exact reference f32 values; see round-6 derivation).
constexpr double grd = 0.05 * (800.0 / (double)Hout);        // 0.05 (f64)
constexpr float  GR  = (float)grd;                            // f32(0.05)
constexpr float  CX0 = (float)(-10.0 + grd / 2.0);            // f32(-9.975)
constexpr float  CY0 = (float)( 46.0 - grd / 2.0);            // f32(45.975)

// Register barrier: keeps ops separately rounded exactly where the numpy
// reference's ufuncs are separately rounded (correctness-critical near the
// g2~0 projective singularity). Coordinate chain ONLY.
__device__ __forceinline__ float fbar(float x) {
    asm volatile("" : "+v"(x));
    return x;
}

struct Samp {
    int   lb0, lb1;           // clamped dwordx2 load bases (row y0 / y1)
    bool  hi0, hi1, xpair;    // corner-select flags
    float w00, w01, w10, w11; // bilinear weights
};

// Bit-exact coordinate chain (verified round 6: flavor-F einsum, IEEE divs,
// separately-rounded ufunc chain). DO NOT TOUCH.
__device__ __forceinline__ Samp px_chain(int w, int h, const float* th, float shn) {
    float bx = CX0 + fbar(GR * (float)w);
    float by = CY0 - fbar(GR * (float)h);

    float t00 = th[0], t01 = th[1], t02 = th[2];
    float t10 = th[3], t11 = th[4], t12 = th[5];
    float t20 = th[6], t21 = th[7], t22 = th[8];

    float g0 = fbar(__builtin_fmaf(by, t01, fbar(bx * t00))) + t02;
    float g1 = fbar(__builtin_fmaf(by, t11, fbar(bx * t10))) + t12;
    float g2 = fbar(__builtin_fmaf(by, t21, fbar(bx * t20))) + t22;

    float p0 = g0 / g2;
    float p1 = g1 / g2;

    float gx = fbar(p0 / 608.0f) - 1.0f;
    float gy = fbar((p1 - shn) / 144.0f) - 1.0f;

    float ix = (fbar((gx + 1.0f) * (float)Win) - 1.0f) * 0.5f;
    float iy = (fbar((gy + 1.0f) * (float)Hin) - 1.0f) * 0.5f;

    float ix0f = floorf(ix);
    float iy0f = floorf(iy);
    float wx = ix - ix0f;
    float wy = iy - iy0f;

    int x0 = (int)fminf(fmaxf(ix0f,        0.0f), (float)(Win - 1));
    int x1 = (int)fminf(fmaxf(ix0f + 1.0f, 0.0f), (float)(Win - 1));
    int y0 = (int)fminf(fmaxf(iy0f,        0.0f), (float)(Hin - 1));
    int y1 = (int)fminf(fmaxf(iy0f + 1.0f, 0.0f), (float)(Hin - 1));

    float omwx = 1.0f - wx;
    float omwy = 1.0f - wy;

    Samp s;
    s.w00 = omwx * omwy;
    s.w01 = wx * omwy;
    s.w10 = omwx * wy;
    s.w11 = wx * wy;

    int lo0 = y0 * Win + x0;
    int lo1 = y1 * Win + x0;
    s.lb0 = min(lo0, CH_STRIDE - 2);
    s.lb1 = min(lo1, CH_STRIDE - 2);
    s.hi0 = lo0 > s.lb0;
    s.hi1 = lo1 > s.lb1;
    s.xpair = x1 > x0;
    return s;
}

__device__ __forceinline__ float combine(float2 r0, float2 r1, const Samp& s) {
    float v00 = s.hi0   ? r0.y : r0.x;
    float v01 = s.xpair ? r0.y : v00;
    float v10 = s.hi1   ? r1.y : r1.x;
    float v11 = s.xpair ? r1.y : v10;
    return v00 * s.w00 + v01 * s.w01 + v10 * s.w10 + v11 * s.w11;
}

__global__ __launch_bounds__(256) void bev_sample_kernel(
    const float* __restrict__ x,      // (N, C, Hin, Win)
    const float* __restrict__ theta,  // (N, 3, 3)
    const float* __restrict__ shift,  // (N,)
    float* __restrict__ out)          // (N, C, Hout, Wout)
{
    // 4 adjacent pixels/thread (w..w+3, w%4==0): cuts VMEM instrs per 4 px
    // from 192 (R10) to 144 = 128 dwordx2 gathers + 16 float4 NT stores.
    // Loads issued channel-major so channel c's 8 loads complete first;
    // compiler pipelines combine+store(c) under later channels' loads
    // (proven in R15: it consumes loads in-order, VGPR stays low).
    int tid4 = blockIdx.x * 256 + threadIdx.x;   // 0..TOTAL/4-1, exact grid
    int pid = tid4 * 4;

    int w0 = pid % Wout;              // multiple of 4; w0+3 < Wout
    int t  = pid / Wout;
    int h  = t % Hout;
    int n  = t / Hout;

    const float* th  = theta + n * 9;
    const float  shn = shift[n];

    Samp s0 = px_chain(w0,     h, th, shn);
    Samp s1 = px_chain(w0 + 1, h, th, shn);
    Samp s2 = px_chain(w0 + 2, h, th, shn);
    Samp s3 = px_chain(w0 + 3, h, th, shn);

    const float* xb = x + (size_t)n * C * CH_STRIDE;

    // Channel-major gather issue: 8 loads per channel (4 px x 2 rows).
    float2 a0[C], a1[C], b0[C], b1[C], c0[C], c1[C], d0[C], d1[C];
    #pragma unroll
    for (int c = 0; c < C; ++c) {
        const float* p = xb + (size_t)c * CH_STRIDE;
        a0[c] = *reinterpret_cast<const float2*>(p + s0.lb0);
        a1[c] = *reinterpret_cast<const float2*>(p + s0.lb1);
        b0[c] = *reinterpret_cast<const float2*>(p + s1.lb0);
        b1[c] = *reinterpret_cast<const float2*>(p + s1.lb1);
        c0[c] = *reinterpret_cast<const float2*>(p + s2.lb0);
        c1[c] = *reinterpret_cast<const float2*>(p + s2.lb1);
        d0[c] = *reinterpret_cast<const float2*>(p + s3.lb0);
        d1[c] = *reinterpret_cast<const float2*>(p + s3.lb1);
    }

    // Combine + 16B NT stores (w0%4==0, Wout%4==0, PIX_PER_N%4==0 -> aligned).
    float* ob = out + ((size_t)(n * C) * Hout + h) * (size_t)Wout + w0;
    #pragma unroll
    for (int c = 0; c < C; ++c) {
        v4f r;
        r.x = combine(a0[c], a1[c], s0);
        r.y = combine(b0[c], b1[c], s1);
        r.z = combine(c0[c], c1[c], s2);
        r.w = combine(d0[c], d1[c], s3);
        __builtin_nontemporal_store(r, reinterpret_cast<v4f*>(
            ob + (size_t)c * PIX_PER_N));
    }
}

extern "C" void kernel_launch(void* const* d_in, const int* in_sizes, int n_in,
                              void* d_out, int out_size, void* d_ws, size_t ws_size,
                              hipStream_t stream) {
    const float* x     = (const float*)d_in[0];
    const float* theta = (const float*)d_in[1];
    const float* shift = (const float*)d_in[2];
    float* out = (float*)d_out;

    int blocks = (TOTAL / 4) / 256;              // 1250, exact
    bev_sample_kernel<<<blocks, 256, 0, stream>>>(x, theta, shift, out);
}

// Round 17
// 40.772 us; speedup vs baseline: 1.0653x; 1.0653x over previous
//
#include <hip/hip_runtime.h>
#include <math.h>

// Problem constants (fixed by setup_inputs)
constexpr int N    = 4;
constexpr int C    = 16;
constexpr int Hin  = 288;
constexpr int Win  = 1216;
constexpr int Hout = 800;
constexpr int Wout = 400;
constexpr int PIX_PER_N = Hout * Wout;       // 320000
constexpr int CH_STRIDE = Hin * Win;         // 350208
constexpr int TOTAL = N * Hout * Wout;       // 1,280,000

typedef float v2f __attribute__((ext_vector_type(2)));

// Base-grid constants (exact reference f32 values; see round-6 derivation).
constexpr double grd = 0.05 * (800.0 / (double)Hout);        // 0.05 (f64)
constexpr float  GR  = (float)grd;                            // f32(0.05)
constexpr float  CX0 = (float)(-10.0 + grd / 2.0);            // f32(-9.975)
constexpr float  CY0 = (float)( 46.0 - grd / 2.0);            // f32(45.975)

// Register barrier: keeps ops separately rounded exactly where the numpy
// reference's ufuncs are separately rounded (correctness-critical near the
// g2~0 projective singularity). Coordinate chain ONLY.
__device__ __forceinline__ float fbar(float x) {
    asm volatile("" : "+v"(x));
    return x;
}

struct Samp {
    int   lb0, lb1;           // clamped dwordx2 load bases (row y0 / y1)
    bool  hi0, hi1, xpair;    // corner-select flags
    float w00, w01, w10, w11; // bilinear weights
};

// Bit-exact coordinate chain (verified round 6: flavor-F einsum, IEEE divs,
// separately-rounded ufunc chain). DO NOT TOUCH.
__device__ __forceinline__ Samp px_chain(int w, int h, const float* th, float shn) {
    float bx = CX0 + fbar(GR * (float)w);
    float by = CY0 - fbar(GR * (float)h);

    float t00 = th[0], t01 = th[1], t02 = th[2];
    float t10 = th[3], t11 = th[4], t12 = th[5];
    float t20 = th[6], t21 = th[7], t22 = th[8];

    float g0 = fbar(__builtin_fmaf(by, t01, fbar(bx * t00))) + t02;
    float g1 = fbar(__builtin_fmaf(by, t11, fbar(bx * t10))) + t12;
    float g2 = fbar(__builtin_fmaf(by, t21, fbar(bx * t20))) + t22;

    float p0 = g0 / g2;
    float p1 = g1 / g2;

    float gx = fbar(p0 / 608.0f) - 1.0f;
    float gy = fbar((p1 - shn) / 144.0f) - 1.0f;

    float ix = (fbar((gx + 1.0f) * (float)Win) - 1.0f) * 0.5f;
    float iy = (fbar((gy + 1.0f) * (float)Hin) - 1.0f) * 0.5f;

    float ix0f = floorf(ix);
    float iy0f = floorf(iy);
    float wx = ix - ix0f;
    float wy = iy - iy0f;

    int x0 = (int)fminf(fmaxf(ix0f,        0.0f), (float)(Win - 1));
    int x1 = (int)fminf(fmaxf(ix0f + 1.0f, 0.0f), (float)(Win - 1));
    int y0 = (int)fminf(fmaxf(iy0f,        0.0f), (float)(Hin - 1));
    int y1 = (int)fminf(fmaxf(iy0f + 1.0f, 0.0f), (float)(Hin - 1));

    float omwx = 1.0f - wx;
    float omwy = 1.0f - wy;

    Samp s;
    s.w00 = omwx * omwy;
    s.w01 = wx * omwy;
    s.w10 = omwx * wy;
    s.w11 = wx * wy;

    int lo0 = y0 * Win + x0;
    int lo1 = y1 * Win + x0;
    s.lb0 = min(lo0, CH_STRIDE - 2);
    s.lb1 = min(lo1, CH_STRIDE - 2);
    s.hi0 = lo0 > s.lb0;
    s.hi1 = lo1 > s.lb1;
    s.xpair = x1 > x0;
    return s;
}

__device__ __forceinline__ float combine(float2 r0, float2 r1, const Samp& s) {
    float v00 = s.hi0   ? r0.y : r0.x;
    float v01 = s.xpair ? r0.y : v00;
    float v10 = s.hi1   ? r1.y : r1.x;
    float v11 = s.xpair ? r1.y : v10;
    return v00 * s.w00 + v01 * s.w01 + v10 * s.w10 + v11 * s.w11;
}

__global__ __launch_bounds__(256) void bev_sample_kernel(
    const float* __restrict__ x,      // (N, C, Hin, Win)
    const float* __restrict__ theta,  // (N, 3, 3)
    const float* __restrict__ shift,  // (N,)
    float* __restrict__ out)          // (N, C, Hout, Wout)
{
    // R15's pipelined 2-px structure (the best so far) with ADJACENT pixels
    // (w, w+1) so the per-pair stores fuse into 16 float2 NT stores:
    // VMEM/px 48 -> 40. No forced drain (R12/R16 failure mode): all 64
    // loads issued before any combine; compiler pipelines in-order.
    int gid = blockIdx.x * 256 + threadIdx.x;   // 0..TOTAL/2-1 (2500 blocks)
    int pid = gid * 2;

    int w = pid % Wout;               // even; w+1 < Wout
    int t = pid / Wout;
    int h = t % Hout;
    int n = t / Hout;
    int ns = __builtin_amdgcn_readfirstlane(n);  // block-uniform (625 blk/n)

    const float* th  = theta + ns * 9;
    const float  shn = shift[ns];

    // Pixel A chain, then issue A gathers.
    Samp sA = px_chain(w, h, th, shn);
    const float* xb = x + (size_t)ns * C * CH_STRIDE;

    float2 rA0[C], rA1[C];
    #pragma unroll
    for (int c = 0; c < C; ++c) {
        const float* p = xb + (size_t)c * CH_STRIDE;
        rA0[c] = *reinterpret_cast<const float2*>(p + sA.lb0);
        rA1[c] = *reinterpret_cast<const float2*>(p + sA.lb1);
    }

    // Pixel B chain overlaps A's load latency; then issue B gathers.
    Samp sB = px_chain(w + 1, h, th, shn);

    float2 rB0[C], rB1[C];
    #pragma unroll
    for (int c = 0; c < C; ++c) {
        const float* p = xb + (size_t)c * CH_STRIDE;
        rB0[c] = *reinterpret_cast<const float2*>(p + sB.lb0);
        rB1[c] = *reinterpret_cast<const float2*>(p + sB.lb1);
    }

    // Combine + fused float2 NT stores (obase even -> 8B aligned).
    size_t obase = ((size_t)(ns * C) * Hout + h) * Wout + w;
    #pragma unroll
    for (int c = 0; c < C; ++c) {
        v2f rr;
        rr.x = combine(rA0[c], rA1[c], sA);
        rr.y = combine(rB0[c], rB1[c], sB);
        __builtin_nontemporal_store(rr, reinterpret_cast<v2f*>(
            &((float*)out)[obase + (size_t)c * PIX_PER_N]));
    }
}

extern "C" void kernel_launch(void* const* d_in, const int* in_sizes, int n_in,
                              void* d_out, int out_size, void* d_ws, size_t ws_size,
                              hipStream_t stream) {
    const float* x     = (const float*)d_in[0];
    const float* theta = (const float*)d_in[1];
    const float* shift = (const float*)d_in[2];
    float* out = (float*)d_out;

    int blocks = (TOTAL / 2) / 256;              // 2500, exact
    bev_sample_kernel<<<blocks, 256, 0, stream>>>(x, theta, shift, out);
}

// Round 18
// 37.138 us; speedup vs baseline: 1.1695x; 1.0979x over previous
//
#include <hip/hip_runtime.h>
#include <math.h>

// Problem constants (fixed by setup_inputs)
constexpr int N    = 4;
constexpr int C    = 16;
constexpr int Hin  = 288;
constexpr int Win  = 1216;
constexpr int Hout = 800;
constexpr int Wout = 400;
constexpr int PIX_PER_N = Hout * Wout;       // 320000
constexpr int CH_STRIDE = Hin * Win;         // 350208
constexpr int TOTAL = N * Hout * Wout;       // 1,280,000
constexpr int HALF  = TOTAL / 2;             // 640,000

// Base-grid constants (exact reference f32 values; see round-6 derivation).
constexpr double grd = 0.05 * (800.0 / (double)Hout);        // 0.05 (f64)
constexpr float  GR  = (float)grd;                            // f32(0.05)
constexpr float  CX0 = (float)(-10.0 + grd / 2.0);            // f32(-9.975)
constexpr float  CY0 = (float)( 46.0 - grd / 2.0);            // f32(45.975)

// Register barrier: keeps ops separately rounded exactly where the numpy
// reference's ufuncs are separately rounded (correctness-critical near the
// g2~0 projective singularity). Coordinate chain ONLY.
__device__ __forceinline__ float fbar(float x) {
    asm volatile("" : "+v"(x));
    return x;
}

struct Samp {
    int   lb0, lb1;           // clamped dwordx2 load bases (row y0 / y1)
    bool  hi0, hi1, xpair;    // corner-select flags
    float w00, w01, w10, w11; // bilinear weights
};

// Bit-exact coordinate chain (verified round 6: flavor-F einsum, IEEE divs,
// separately-rounded ufunc chain). DO NOT TOUCH.
__device__ __forceinline__ Samp px_chain(int w, int h, const float* th, float shn) {
    float bx = CX0 + fbar(GR * (float)w);
    float by = CY0 - fbar(GR * (float)h);

    float t00 = th[0], t01 = th[1], t02 = th[2];
    float t10 = th[3], t11 = th[4], t12 = th[5];
    float t20 = th[6], t21 = th[7], t22 = th[8];

    float g0 = fbar(__builtin_fmaf(by, t01, fbar(bx * t00))) + t02;
    float g1 = fbar(__builtin_fmaf(by, t11, fbar(bx * t10))) + t12;
    float g2 = fbar(__builtin_fmaf(by, t21, fbar(bx * t20))) + t22;

    float p0 = g0 / g2;
    float p1 = g1 / g2;

    float gx = fbar(p0 / 608.0f) - 1.0f;
    float gy = fbar((p1 - shn) / 144.0f) - 1.0f;

    float ix = (fbar((gx + 1.0f) * (float)Win) - 1.0f) * 0.5f;
    float iy = (fbar((gy + 1.0f) * (float)Hin) - 1.0f) * 0.5f;

    float ix0f = floorf(ix);
    float iy0f = floorf(iy);
    float wx = ix - ix0f;
    float wy = iy - iy0f;

    int x0 = (int)fminf(fmaxf(ix0f,        0.0f), (float)(Win - 1));
    int x1 = (int)fminf(fmaxf(ix0f + 1.0f, 0.0f), (float)(Win - 1));
    int y0 = (int)fminf(fmaxf(iy0f,        0.0f), (float)(Hin - 1));
    int y1 = (int)fminf(fmaxf(iy0f + 1.0f, 0.0f), (float)(Hin - 1));

    float omwx = 1.0f - wx;
    float omwy = 1.0f - wy;

    Samp s;
    s.w00 = omwx * omwy;
    s.w01 = wx * omwy;
    s.w10 = omwx * wy;
    s.w11 = wx * wy;

    int lo0 = y0 * Win + x0;
    int lo1 = y1 * Win + x0;
    s.lb0 = min(lo0, CH_STRIDE - 2);
    s.lb1 = min(lo1, CH_STRIDE - 2);
    s.hi0 = lo0 > s.lb0;
    s.hi1 = lo1 > s.lb1;
    s.xpair = x1 > x0;
    return s;
}

__device__ __forceinline__ float combine(float2 r0, float2 r1, const Samp& s) {
    float v00 = s.hi0   ? r0.y : r0.x;
    float v01 = s.xpair ? r0.y : v00;
    float v10 = s.hi1   ? r1.y : r1.x;
    float v11 = s.xpair ? r1.y : v10;
    return v00 * s.w00 + v01 * s.w01 + v10 * s.w10 + v11 * s.w11;
}

__global__ __launch_bounds__(256) void bev_sample_kernel(
    const float* __restrict__ x,      // (N, C, Hin, Win)
    const float* __restrict__ theta,  // (N, 3, 3)
    const float* __restrict__ shift,  // (N,)
    float* __restrict__ out)          // (N, C, Hout, Wout)
{
    // R15 winning structure + ONE change: sched_barrier(0) after all 64
    // loads, forbidding the scheduler from interleaving combine/vmcnt waits
    // into the load region. Forces full-depth MLP (one overlapped L2
    // round-trip instead of ~16 serialized partial waits per wave).
    int gid = blockIdx.x * 256 + threadIdx.x;   // 0..HALF-1 (2500 blocks)

    // ---------------- pixel A ----------------
    int wA = gid % Wout;
    int tA = gid / Wout;
    int hA = tA % Hout;
    int nA = tA / Hout;
    int nAs = __builtin_amdgcn_readfirstlane(nA);

    Samp sA = px_chain(wA, hA, theta + nAs * 9, shift[nAs]);
    const float* xbA = x + (size_t)nAs * C * CH_STRIDE;

    float2 rA0[C], rA1[C];
    #pragma unroll
    for (int c = 0; c < C; ++c) {
        const float* p = xbA + (size_t)c * CH_STRIDE;
        rA0[c] = *reinterpret_cast<const float2*>(p + sA.lb0);
        rA1[c] = *reinterpret_cast<const float2*>(p + sA.lb1);
    }

    // ---------------- pixel B (chain overlaps A's loads) ----------------
    int pidB = gid + HALF;
    int wB = pidB % Wout;
    int tB = pidB / Wout;
    int hB = tB % Hout;
    int nB = tB / Hout;
    int nBs = __builtin_amdgcn_readfirstlane(nB);

    Samp sB = px_chain(wB, hB, theta + nBs * 9, shift[nBs]);
    const float* xbB = x + (size_t)nBs * C * CH_STRIDE;

    float2 rB0[C], rB1[C];
    #pragma unroll
    for (int c = 0; c < C; ++c) {
        const float* p = xbB + (size_t)c * CH_STRIDE;
        rB0[c] = *reinterpret_cast<const float2*>(p + sB.lb0);
        rB1[c] = *reinterpret_cast<const float2*>(p + sB.lb1);
    }

    // All 64 loads issued; nothing below may be scheduled above this point.
    __builtin_amdgcn_sched_barrier(0);

    // ---------------- combine + NT store A ----------------
    size_t obA = ((size_t)(nAs * C) * Hout + hA) * Wout + wA;
    #pragma unroll
    for (int c = 0; c < C; ++c) {
        float r = combine(rA0[c], rA1[c], sA);
        __builtin_nontemporal_store(r, &out[obA + (size_t)c * PIX_PER_N]);
    }

    // ---------------- combine + NT store B ----------------
    size_t obB = ((size_t)(nBs * C) * Hout + hB) * Wout + wB;
    #pragma unroll
    for (int c = 0; c < C; ++c) {
        float r = combine(rB0[c], rB1[c], sB);
        __builtin_nontemporal_store(r, &out[obB + (size_t)c * PIX_PER_N]);
    }
}

extern "C" void kernel_launch(void* const* d_in, const int* in_sizes, int n_in,
                              void* d_out, int out_size, void* d_ws, size_t ws_size,
                              hipStream_t stream) {
    const float* x     = (const float*)d_in[0];
    const float* theta = (const float*)d_in[1];
    const float* shift = (const float*)d_in[2];
    float* out = (float*)d_out;

    int blocks = HALF / 256;                     // 2500, exact
    bev_sample_kernel<<<blocks, 256, 0, stream>>>(x, theta, shift, out);
}